// Round 4
// baseline (462.428 us; speedup 1.0000x reference)
//
#include <hip/hip_runtime.h>
#include <hip/hip_bf16.h>

#define NNX 256
#define CCX 128
#define HHX 4
#define CHDX 32
#define NIJ (NNX*NNX)

typedef __hip_bfloat16 bf16;
typedef __hip_bfloat162 bf162;
typedef __attribute__((ext_vector_type(8))) short short8v;
typedef __attribute__((ext_vector_type(4))) float float4v;

__device__ __forceinline__ float4v MFMA(short8v a, short8v b, float4v c){
  return __builtin_amdgcn_mfma_f32_16x16x32_bf16(a, b, c, 0, 0, 0);
}

__device__ __forceinline__ unsigned pk2(float a, float b){
  unsigned short ua = __bfloat16_as_ushort(__float2bfloat16(a));
  unsigned short ub = __bfloat16_as_ushort(__float2bfloat16(b));
  return (unsigned)ua | ((unsigned)ub << 16);
}
__device__ __forceinline__ float ubf(unsigned short u){
  return __bfloat162float(__ushort_as_bfloat16(u));
}

__device__ __forceinline__ void load8bf16(const bf16* p, float* f){
  const bf162* p2 = (const bf162*)p;
  #pragma unroll
  for(int t=0;t<4;++t){ float2 xy = __bfloat1622float2(p2[t]); f[2*t]=xy.x; f[2*t+1]=xy.y; }
}

// cmap [C, I, J] -> x [I, J, C]
__global__ __launch_bounds__(256) void k_tin(const float* __restrict__ in, float* __restrict__ out){
  __shared__ float t[32][33];
  const int i = blockIdx.z, jt = blockIdx.x, ct = blockIdx.y;
  const int tx = threadIdx.x, ty = threadIdx.y; // 32, 8
  #pragma unroll
  for(int k=0;k<32;k+=8){
    int c = ct*32 + ty + k;
    t[ty+k][tx] = in[(size_t)c*NIJ + (size_t)i*NNX + jt*32 + tx];
  }
  __syncthreads();
  #pragma unroll
  for(int k=0;k<32;k+=8){
    int j = jt*32 + ty + k;
    out[((size_t)i*NNX + j)*CCX + ct*32 + tx] = t[tx][ty+k];
  }
}

// x [I,J,C] -> out [C,I,J]
__global__ __launch_bounds__(256) void k_tout(const float* __restrict__ x, float* __restrict__ out){
  __shared__ float t[32][33];
  const int i = blockIdx.z, jt = blockIdx.x, ct = blockIdx.y;
  const int tx = threadIdx.x, ty = threadIdx.y;
  #pragma unroll
  for(int k=0;k<32;k+=8){
    t[ty+k][tx] = x[((size_t)i*NNX + jt*32+ty+k)*CCX + ct*32 + tx];
  }
  __syncthreads();
  #pragma unroll
  for(int k=0;k<32;k+=8){
    out[(size_t)(ct*32+ty+k)*NIJ + (size_t)i*NNX + jt*32 + tx] = t[tx][ty+k];
  }
}

// fused LayerNorm + triangle-bias projection. One wave per row, thread = 2 channels.
template<int TRANS>
__global__ __launch_bounds__(256) void k_lntb(const float* __restrict__ x,
    const float* __restrict__ w, const float* __restrict__ b,
    const float* __restrict__ wz, bf16* __restrict__ xln, float* __restrict__ tb2){
  const int r = blockIdx.x*4 + threadIdx.y;
  const int ii = r>>8, jj = r&255;
  const float* src = x + (size_t)(TRANS ? (jj*NNX+ii) : r)*CCX;
  const int c = threadIdx.x*2;
  float2 v = *(const float2*)(src+c);
  float s = v.x+v.y, s2 = v.x*v.x+v.y*v.y;
  #pragma unroll
  for(int off=32; off>0; off>>=1){ s += __shfl_xor(s,off); s2 += __shfl_xor(s2,off); }
  float mu = s*0.0078125f;
  float var = s2*0.0078125f - mu*mu;
  float rs = rsqrtf(var+1e-5f);
  float a0 = (v.x-mu)*rs*w[c]+b[c];
  float a1 = (v.y-mu)*rs*w[c+1]+b[c+1];
  bf162 hp; hp.x = __float2bfloat16(a0); hp.y = __float2bfloat16(a1);
  *(bf162*)(xln + (size_t)r*CCX + c) = hp;
  // tb = x_ln @ wz  (wz: [128][4])
  float acc[4];
  #pragma unroll
  for(int hh=0;hh<4;++hh) acc[hh] = a0*wz[c*4+hh] + a1*wz[(c+1)*4+hh];
  #pragma unroll
  for(int off=32; off>0; off>>=1){
    #pragma unroll
    for(int hh=0;hh<4;++hh) acc[hh] += __shfl_xor(acc[hh], off);
  }
  if(threadIdx.x==0){
    #pragma unroll
    for(int hh=0;hh<4;++hh) tb2[(size_t)hh*NIJ + r] = acc[hh];
  }
}

// convert+transpose weights:
//   wT [n][k], n in [0,512): {wq,wk,wv,wg}^T
//   wT+65536: woT [n][k], n in [0,128): wo^T
__global__ __launch_bounds__(256) void k_cvtw(const float* __restrict__ wq,
    const float* __restrict__ wk, const float* __restrict__ wv,
    const float* __restrict__ wg, const float* __restrict__ wo, bf16* __restrict__ wT){
  int idx = blockIdx.x*256 + threadIdx.x;   // 81920
  if(idx < 65536){
    int n = idx >> 7, k = idx & 127;
    const float* W = (n<128)?wq:(n<256)?wk:(n<384)?wv:wg;
    wT[idx] = __float2bfloat16(W[k*CCX + (n&127)]);
  } else {
    int idx2 = idx - 65536;
    int n = idx2 >> 7, k = idx2 & 127;
    wT[idx] = __float2bfloat16(wo[k*CCX + n]);
  }
}

// MFMA projection: out^T tiles = mfma(A = wT tile [16n x 32k], B = xln^T [32k x 16m])
__global__ __launch_bounds__(256) void k_projm(const bf16* __restrict__ xln,
    const bf16* __restrict__ wT, const float* __restrict__ bg,
    bf16* __restrict__ qb, bf16* __restrict__ kb, bf16* __restrict__ vb, bf16* __restrict__ gb){
  const int tid = threadIdx.x;
  const int w = tid >> 6, l = tid & 63;
  const int lq = l & 15, g = l >> 4;
  const int mbase = blockIdx.x*128 + w*32;
  short8v bx[2][4];
  #pragma unroll
  for(int ms=0; ms<2; ++ms){
    const size_t mrow = mbase + ms*16 + lq;
    #pragma unroll
    for(int kc=0; kc<4; ++kc)
      bx[ms][kc] = *(const short8v*)(xln + mrow*CCX + kc*32 + g*8);
  }
  for(int nj=0; nj<32; ++nj){
    float4v acc0 = (float4v)(0.f), acc1 = (float4v)(0.f);
    #pragma unroll
    for(int kc=0; kc<4; ++kc){
      short8v aw = *(const short8v*)(wT + (size_t)(nj*16 + lq)*CCX + kc*32 + g*8);
      acc0 = MFMA(aw, bx[0][kc], acc0);
      acc1 = MFMA(aw, bx[1][kc], acc1);
    }
    const int mat = nj >> 3;
    const int col = (nj&7)*16 + 4*g;
    bf16* outp = (mat==0)?qb:(mat==1)?kb:(mat==2)?vb:gb;
    #pragma unroll
    for(int ms=0; ms<2; ++ms){
      const size_t mrow = mbase + ms*16 + lq;
      float v0 = (ms==0)?acc0[0]:acc1[0], v1 = (ms==0)?acc0[1]:acc1[1];
      float v2 = (ms==0)?acc0[2]:acc1[2], v3 = (ms==0)?acc0[3]:acc1[3];
      if(mat==0){ v0*=0.17677669529663687f; v1*=0.17677669529663687f;
                  v2*=0.17677669529663687f; v3*=0.17677669529663687f; }
      if(mat==3){ v0+=bg[col]; v1+=bg[col+1]; v2+=bg[col+2]; v3+=bg[col+3]; }
      uint2 pw; pw.x = pk2(v0,v1); pw.y = pk2(v2,v3);
      *(uint2*)(outp + mrow*CCX + col) = pw;
    }
  }
}

// MFMA attention per (i,h). 4 waves; wave handles 64 q (4 subtiles of 16).
// S^T = mfma(K_tile, Q^T, bias) ; softmax ; O^T = mfma(V'_perm^T, P-from-regs).
// V is staged k-PERMUTED so each lane's own exp() values form a valid PV B-frag:
//   kappa(k): j=k&31 -> 32*(k>>5) + 8*((j>>2)&3) + 4*((j>>4)&1) + (j&3)
__global__ __launch_bounds__(256,4) void k_attnm(const bf16* __restrict__ qp,
    const bf16* __restrict__ kp, const bf16* __restrict__ vp,
    const bf16* __restrict__ gp, const float* __restrict__ tb2,
    bf16* __restrict__ op){
  __shared__ unsigned short KsA[256*40];     // 20KB  K row-major [k][d], 80B pitch
  __shared__ unsigned short VtA[32*256];     // 16KB  V^T [d][kappa], XOR-swizzled
  const int i = blockIdx.x, h = blockIdx.y;
  const int tid = threadIdx.x;
  const int w = tid >> 6, l = tid & 63;
  const int lq = l & 15, g = l >> 4;

  // ---- stage K (80B pitch) and permuted V^T (swizzled): thread = one k-row ----
  {
    const int k = tid;
    const bf16* ksrc = kp + ((size_t)(i*NNX + k))*CCX + h*CHDX;
    *(short8v*)(&KsA[k*40])      = *(const short8v*)(ksrc);
    *(short8v*)(&KsA[k*40+8])    = *(const short8v*)(ksrc+8);
    *(short8v*)(&KsA[k*40+16])   = *(const short8v*)(ksrc+16);
    *(short8v*)(&KsA[k*40+24])   = *(const short8v*)(ksrc+24);
    const bf16* vsrc = vp + ((size_t)(i*NNX + k))*CCX + h*CHDX;
    short8v vv[4];
    vv[0] = *(const short8v*)(vsrc);
    vv[1] = *(const short8v*)(vsrc+8);
    vv[2] = *(const short8v*)(vsrc+16);
    vv[3] = *(const short8v*)(vsrc+24);
    const int j = k & 31;
    const int kap = (k & ~31) + 8*((j>>2)&3) + 4*((j>>4)&1) + (j&3);
    char* vtb = (char*)VtA;
    #pragma unroll
    for(int c4=0;c4<4;++c4){
      #pragma unroll
      for(int e=0;e<8;++e){
        int d = c4*8+e;
        int off = d*512 + ((2*kap) ^ ((d&7)<<4));
        *(short*)(vtb + off) = vv[c4][e];
      }
    }
  }
  __syncthreads();

  const char* ktb = (const char*)KsA;
  const char* vtb = (const char*)VtA;

  #pragma unroll 1
  for(int sub=0; sub<4; ++sub){
    const int q = w*64 + sub*16 + lq;
    const size_t qrow = (size_t)i*NNX + q;
    short8v qf = *(const short8v*)(qp + qrow*CCX + h*CHDX + g*8);
    const float* tbq = tb2 + (size_t)h*NIJ + (size_t)q*NNX;
    float4v s[16];
    // QK^T with bias fused as the MFMA C-operand
    #pragma unroll
    for(int t=0;t<16;++t){
      short8v ak = *(const short8v*)(ktb + (t*16 + lq)*80 + g*16);
      float4v bb = *(const float4v*)(tbq + t*16 + g*4);
      s[t] = MFMA(ak, qf, bb);
    }
    // row max over own 64 + lane groups
    float m = -1e30f;
    #pragma unroll
    for(int t=0;t<16;++t)
      m = fmaxf(m, fmaxf(fmaxf(s[t][0], s[t][1]), fmaxf(s[t][2], s[t][3])));
    m = fmaxf(m, __shfl_xor(m,16));
    m = fmaxf(m, __shfl_xor(m,32));
    float lsum = 0.f;
    #pragma unroll
    for(int t=0;t<16;++t){
      #pragma unroll
      for(int r=0;r<4;++r){ float e = __expf(s[t][r]-m); s[t][r]=e; lsum+=e; }
    }
    lsum += __shfl_xor(lsum,16);
    lsum += __shfl_xor(lsum,32);
    const float linv = 1.0f/lsum;
    // PV directly from registers: B-frag chunk c = {s[2c][0..3], s[2c+1][0..3]} as bf16
    #pragma unroll
    for(int dt=0; dt<2; ++dt){
      float4v acc = (float4v)(0.f);
      #pragma unroll
      for(int c=0;c<8;++c){
        const int vrow = dt*16 + lq;
        short8v av = *(const short8v*)(vtb + vrow*512 + ((16*g + 64*c) ^ ((vrow&7)<<4)));
        uint4 pb;
        pb.x = pk2(s[2*c][0],   s[2*c][1]);
        pb.y = pk2(s[2*c][2],   s[2*c][3]);
        pb.z = pk2(s[2*c+1][0], s[2*c+1][1]);
        pb.w = pk2(s[2*c+1][2], s[2*c+1][3]);
        short8v bp;
        bp[0]=(short)(pb.x&0xffff); bp[1]=(short)(pb.x>>16);
        bp[2]=(short)(pb.y&0xffff); bp[3]=(short)(pb.y>>16);
        bp[4]=(short)(pb.z&0xffff); bp[5]=(short)(pb.z>>16);
        bp[6]=(short)(pb.w&0xffff); bp[7]=(short)(pb.w>>16);
        acc = MFMA(av, bp, acc);
      }
      const size_t eoff = qrow*CCX + h*CHDX + dt*16 + g*4;
      uint2 gw = *(const uint2*)(gp + eoff);
      float g0 = ubf((unsigned short)(gw.x & 0xffff));
      float g1 = ubf((unsigned short)(gw.x >> 16));
      float g2 = ubf((unsigned short)(gw.y & 0xffff));
      float g3 = ubf((unsigned short)(gw.y >> 16));
      float o0 = acc[0]*linv / (1.f + __expf(-g0));
      float o1 = acc[1]*linv / (1.f + __expf(-g1));
      float o2 = acc[2]*linv / (1.f + __expf(-g2));
      float o3 = acc[3]*linv / (1.f + __expf(-g3));
      uint2 ow; ow.x = pk2(o0,o1); ow.y = pk2(o2,o3);
      *(uint2*)(op + eoff) = ow;
    }
  }
}

// MFMA o-projection + residual: x += o @ wo + bo  (optionally scattered for TRANS)
template<int TRANS>
__global__ __launch_bounds__(256) void k_oprojm(const bf16* __restrict__ ob,
    const bf16* __restrict__ woT, const float* __restrict__ bo, float* __restrict__ x){
  const int tid = threadIdx.x;
  const int w = tid >> 6, l = tid & 63;
  const int lq = l & 15, g = l >> 4;
  const int mbase = blockIdx.x*128 + w*32;
  short8v bx[2][4];
  #pragma unroll
  for(int ms=0; ms<2; ++ms){
    const size_t mrow = mbase + ms*16 + lq;
    #pragma unroll
    for(int kc=0; kc<4; ++kc)
      bx[ms][kc] = *(const short8v*)(ob + mrow*CCX + kc*32 + g*8);
  }
  #pragma unroll
  for(int nj=0; nj<8; ++nj){
    float4v acc0 = (float4v)(0.f), acc1 = (float4v)(0.f);
    #pragma unroll
    for(int kc=0; kc<4; ++kc){
      short8v aw = *(const short8v*)(woT + (size_t)(nj*16 + lq)*CCX + kc*32 + g*8);
      acc0 = MFMA(aw, bx[0][kc], acc0);
      acc1 = MFMA(aw, bx[1][kc], acc1);
    }
    const int col = nj*16 + 4*g;
    const float4 bo4 = *(const float4*)(bo + col);
    #pragma unroll
    for(int ms=0; ms<2; ++ms){
      const int r = mbase + ms*16 + lq;
      const int ii = r>>8, jj = r&255;
      float* dst = x + (size_t)(TRANS ? (jj*NNX+ii) : r)*CCX + col;
      float4 xv = *(float4*)dst;
      xv.x += ((ms==0)?acc0[0]:acc1[0]) + bo4.x;
      xv.y += ((ms==0)?acc0[1]:acc1[1]) + bo4.y;
      xv.z += ((ms==0)?acc0[2]:acc1[2]) + bo4.z;
      xv.w += ((ms==0)?acc0[3]:acc1[3]) + bo4.w;
      *(float4*)dst = xv;
    }
  }
}

extern "C" void kernel_launch(void* const* d_in, const int* in_sizes, int n_in,
                              void* d_out, int out_size, void* d_ws, size_t ws_size,
                              hipStream_t stream){
  const float* cmap = (const float*)d_in[0];
  char* ws = (char*)d_ws;
  float* x   = (float*)(ws);
  bf16* xln  = (bf16*)(ws + 33554432);
  bf16* ob   = xln;                       // alias: xln dead after k_projm
  bf16* qb   = (bf16*)(ws + 50331648);
  bf16* kb   = (bf16*)(ws + 67108864);
  bf16* vb   = (bf16*)(ws + 83886080);
  bf16* gb   = (bf16*)(ws + 100663296);
  float* tb2 = (float*)(ws + 117440512);
  bf16* wT   = (bf16*)d_out;              // 160KB scratch at head of d_out; k_tout overwrites last
  bf16* woT  = wT + 65536;
  float* outp = (float*)d_out;

  k_tin<<<dim3(8,4,NNX), dim3(32,8), 0, stream>>>(cmap, x);

  for(int p=0;p<2;++p){
    const int b = 1 + 10*p;
    const float* lnw = (const float*)d_in[b+0];
    const float* lnb = (const float*)d_in[b+1];
    const float* wq  = (const float*)d_in[b+2];
    const float* wk  = (const float*)d_in[b+3];
    const float* wv  = (const float*)d_in[b+4];
    const float* wz  = (const float*)d_in[b+5];
    const float* wg  = (const float*)d_in[b+6];
    const float* bg  = (const float*)d_in[b+7];
    const float* wo  = (const float*)d_in[b+8];
    const float* bo  = (const float*)d_in[b+9];

    k_cvtw<<<320, 256, 0, stream>>>(wq, wk, wv, wg, wo, wT);

    if(p==0) k_lntb<0><<<NIJ/4, dim3(64,4), 0, stream>>>(x, lnw, lnb, wz, xln, tb2);
    else     k_lntb<1><<<NIJ/4, dim3(64,4), 0, stream>>>(x, lnw, lnb, wz, xln, tb2);

    k_projm<<<NIJ/128, 256, 0, stream>>>(xln, wT, bg, qb, kb, vb, gb);

    k_attnm<<<dim3(NNX,HHX), 256, 0, stream>>>(qb, kb, vb, gb, tb2, ob);

    if(p==0) k_oprojm<0><<<NIJ/128, 256, 0, stream>>>(ob, woT, bo, x);
    else     k_oprojm<1><<<NIJ/128, 256, 0, stream>>>(ob, woT, bo, x);
  }

  k_tout<<<dim3(8,4,NNX), dim3(32,8), 0, stream>>>(x, outp);
}

// Round 5
// 445.538 us; speedup vs baseline: 1.0379x; 1.0379x over previous
//
#include <hip/hip_runtime.h>
#include <hip/hip_bf16.h>

#define NNX 256
#define CCX 128
#define HHX 4
#define CHDX 32
#define NIJ (NNX*NNX)

typedef __hip_bfloat16 bf16;
typedef __hip_bfloat162 bf162;
typedef __attribute__((ext_vector_type(8))) short short8v;
typedef __attribute__((ext_vector_type(4))) float float4v;

__device__ __forceinline__ float4v MFMA(short8v a, short8v b, float4v c){
  return __builtin_amdgcn_mfma_f32_16x16x32_bf16(a, b, c, 0, 0, 0);
}

__device__ __forceinline__ unsigned pk2(float a, float b){
  unsigned short ua = __bfloat16_as_ushort(__float2bfloat16(a));
  unsigned short ub = __bfloat16_as_ushort(__float2bfloat16(b));
  return (unsigned)ua | ((unsigned)ub << 16);
}
__device__ __forceinline__ float ubf(unsigned short u){
  return __bfloat162float(__ushort_as_bfloat16(u));
}

__device__ __forceinline__ void load8bf16(const bf16* p, float* f){
  const bf162* p2 = (const bf162*)p;
  #pragma unroll
  for(int t=0;t<4;++t){ float2 xy = __bfloat1622float2(p2[t]); f[2*t]=xy.x; f[2*t+1]=xy.y; }
}

// cmap [C, I, J] -> x [I, J, C]
__global__ __launch_bounds__(256) void k_tin(const float* __restrict__ in, float* __restrict__ out){
  __shared__ float t[32][33];
  const int i = blockIdx.z, jt = blockIdx.x, ct = blockIdx.y;
  const int tx = threadIdx.x, ty = threadIdx.y; // 32, 8
  #pragma unroll
  for(int k=0;k<32;k+=8){
    int c = ct*32 + ty + k;
    t[ty+k][tx] = in[(size_t)c*NIJ + (size_t)i*NNX + jt*32 + tx];
  }
  __syncthreads();
  #pragma unroll
  for(int k=0;k<32;k+=8){
    int j = jt*32 + ty + k;
    out[((size_t)i*NNX + j)*CCX + ct*32 + tx] = t[tx][ty+k];
  }
}

// x [I,J,C] -> out [C,I,J]
__global__ __launch_bounds__(256) void k_tout(const float* __restrict__ x, float* __restrict__ out){
  __shared__ float t[32][33];
  const int i = blockIdx.z, jt = blockIdx.x, ct = blockIdx.y;
  const int tx = threadIdx.x, ty = threadIdx.y;
  #pragma unroll
  for(int k=0;k<32;k+=8){
    t[ty+k][tx] = x[((size_t)i*NNX + jt*32+ty+k)*CCX + ct*32 + tx];
  }
  __syncthreads();
  #pragma unroll
  for(int k=0;k<32;k+=8){
    out[(size_t)(ct*32+ty+k)*NIJ + (size_t)i*NNX + jt*32 + tx] = t[tx][ty+k];
  }
}

// fused LayerNorm + triangle-bias projection. One wave per row, thread = 2 channels.
template<int TRANS>
__global__ __launch_bounds__(256) void k_lntb(const float* __restrict__ x,
    const float* __restrict__ w, const float* __restrict__ b,
    const float* __restrict__ wz, bf16* __restrict__ xln, float* __restrict__ tb2){
  const int r = blockIdx.x*4 + threadIdx.y;
  const int ii = r>>8, jj = r&255;
  const float* src = x + (size_t)(TRANS ? (jj*NNX+ii) : r)*CCX;
  const int c = threadIdx.x*2;
  float2 v = *(const float2*)(src+c);
  float s = v.x+v.y, s2 = v.x*v.x+v.y*v.y;
  #pragma unroll
  for(int off=32; off>0; off>>=1){ s += __shfl_xor(s,off); s2 += __shfl_xor(s2,off); }
  float mu = s*0.0078125f;
  float var = s2*0.0078125f - mu*mu;
  float rs = rsqrtf(var+1e-5f);
  float a0 = (v.x-mu)*rs*w[c]+b[c];
  float a1 = (v.y-mu)*rs*w[c+1]+b[c+1];
  bf162 hp; hp.x = __float2bfloat16(a0); hp.y = __float2bfloat16(a1);
  *(bf162*)(xln + (size_t)r*CCX + c) = hp;
  // tb = x_ln @ wz  (wz: [128][4])
  float acc[4];
  #pragma unroll
  for(int hh=0;hh<4;++hh) acc[hh] = a0*wz[c*4+hh] + a1*wz[(c+1)*4+hh];
  #pragma unroll
  for(int off=32; off>0; off>>=1){
    #pragma unroll
    for(int hh=0;hh<4;++hh) acc[hh] += __shfl_xor(acc[hh], off);
  }
  if(threadIdx.x==0){
    #pragma unroll
    for(int hh=0;hh<4;++hh) tb2[(size_t)hh*NIJ + r] = acc[hh];
  }
}

// convert+transpose weights:
//   wT [n][k], n in [0,512): {wq,wk,wv,wg}^T
//   wT+65536: woT [n][k], n in [0,128): wo^T
__global__ __launch_bounds__(256) void k_cvtw(const float* __restrict__ wq,
    const float* __restrict__ wk, const float* __restrict__ wv,
    const float* __restrict__ wg, const float* __restrict__ wo, bf16* __restrict__ wT){
  int idx = blockIdx.x*256 + threadIdx.x;   // 81920
  if(idx < 65536){
    int n = idx >> 7, k = idx & 127;
    const float* W = (n<128)?wq:(n<256)?wk:(n<384)?wv:wg;
    wT[idx] = __float2bfloat16(W[k*CCX + (n&127)]);
  } else {
    int idx2 = idx - 65536;
    int n = idx2 >> 7, k = idx2 & 127;
    wT[idx] = __float2bfloat16(wo[k*CCX + n]);
  }
}

// MFMA projection: out^T tiles = mfma(A = wT tile [16n x 32k], B = xln^T [32k x 16m])
// Outputs q/k/v/g in HEAD-MAJOR layout: [H][NIJ][32].
__global__ __launch_bounds__(256) void k_projm(const bf16* __restrict__ xln,
    const bf16* __restrict__ wT, const float* __restrict__ bg,
    bf16* __restrict__ qb, bf16* __restrict__ kb, bf16* __restrict__ vb, bf16* __restrict__ gb){
  const int tid = threadIdx.x;
  const int w = tid >> 6, l = tid & 63;
  const int lq = l & 15, g = l >> 4;
  const int mbase = blockIdx.x*128 + w*32;
  short8v bx[2][4];
  #pragma unroll
  for(int ms=0; ms<2; ++ms){
    const size_t mrow = mbase + ms*16 + lq;
    #pragma unroll
    for(int kc=0; kc<4; ++kc)
      bx[ms][kc] = *(const short8v*)(xln + mrow*CCX + kc*32 + g*8);
  }
  for(int nj=0; nj<32; ++nj){
    float4v acc0 = (float4v)(0.f), acc1 = (float4v)(0.f);
    #pragma unroll
    for(int kc=0; kc<4; ++kc){
      short8v aw = *(const short8v*)(wT + (size_t)(nj*16 + lq)*CCX + kc*32 + g*8);
      acc0 = MFMA(aw, bx[0][kc], acc0);
      acc1 = MFMA(aw, bx[1][kc], acc1);
    }
    const int mat = nj >> 3;
    const int col = (nj&7)*16 + 4*g;      // [0,128)
    const int hh = col >> 5, cc = col & 31;
    bf16* outp = (mat==0)?qb:(mat==1)?kb:(mat==2)?vb:gb;
    #pragma unroll
    for(int ms=0; ms<2; ++ms){
      const size_t mrow = mbase + ms*16 + lq;
      float v0 = (ms==0)?acc0[0]:acc1[0], v1 = (ms==0)?acc0[1]:acc1[1];
      float v2 = (ms==0)?acc0[2]:acc1[2], v3 = (ms==0)?acc0[3]:acc1[3];
      if(mat==0){ v0*=0.17677669529663687f; v1*=0.17677669529663687f;
                  v2*=0.17677669529663687f; v3*=0.17677669529663687f; }
      if(mat==3){ v0+=bg[col]; v1+=bg[col+1]; v2+=bg[col+2]; v3+=bg[col+3]; }
      uint2 pw; pw.x = pk2(v0,v1); pw.y = pk2(v2,v3);
      *(uint2*)(outp + ((size_t)hh*NIJ + mrow)*CHDX + cc) = pw;
    }
  }
}

// MFMA attention per (i,h). All q/k/v/g/o in head-major [H][NIJ][32] -> contiguous streams.
// S^T = mfma(K_tile, Q^T, bias) ; softmax ; O^T = mfma(V'_perm^T, P-from-regs).
//   kappa(k): j=k&31 -> (k&~31) + 8*((j>>2)&3) + 4*((j>>4)&1) + (j&3)
__global__ __launch_bounds__(256,4) void k_attnm(const bf16* __restrict__ qp,
    const bf16* __restrict__ kp, const bf16* __restrict__ vp,
    const bf16* __restrict__ gp, const float* __restrict__ tb2,
    bf16* __restrict__ op){
  __shared__ unsigned short KsA[256*40];     // 20KB  K row-major [k][d], 80B pitch
  __shared__ unsigned short VtA[32*256];     // 16KB  V^T [d][kappa], XOR-swizzled
  const int i = blockIdx.x, h = blockIdx.y;
  const int tid = threadIdx.x;
  const int w = tid >> 6, l = tid & 63;
  const int lq = l & 15, g = l >> 4;

  const bf16* kbh = kp + ((size_t)h*NIJ + (size_t)i*NNX)*CHDX;
  const bf16* vbh = vp + ((size_t)h*NIJ + (size_t)i*NNX)*CHDX;
  const bf16* qbh = qp + ((size_t)h*NIJ + (size_t)i*NNX)*CHDX;
  const bf16* gbh = gp + ((size_t)h*NIJ + (size_t)i*NNX)*CHDX;
  bf16*       obh = op + ((size_t)h*NIJ + (size_t)i*NNX)*CHDX;

  // ---- stage K (flat coalesced copy, 80B pitch) ----
  #pragma unroll
  for(int it=0; it<4; ++it){
    int idx = tid + it*256;            // [0,1024), 16B each
    int row = idx>>2, seg = (idx&3)*8;
    *(short8v*)(&KsA[row*40 + seg]) = *(const short8v*)(kbh + (size_t)idx*8);
  }
  // ---- stage permuted V^T (swizzled scatter from coalesced loads) ----
  {
    char* vtb = (char*)VtA;
    #pragma unroll
    for(int it=0; it<4; ++it){
      int idx = tid + it*256;
      int row = idx>>2, seg = (idx&3)*8;
      short8v vv = *(const short8v*)(vbh + (size_t)idx*8);
      const int j = row & 31;
      const int kap = (row & ~31) + 8*((j>>2)&3) + 4*((j>>4)&1) + (j&3);
      #pragma unroll
      for(int e=0;e<8;++e){
        int d = seg+e;
        int off = d*512 + ((2*kap) ^ ((d&7)<<4));
        *(short*)(vtb + off) = vv[e];
      }
    }
  }
  __syncthreads();

  const char* ktb = (const char*)KsA;
  const char* vtb = (const char*)VtA;

  #pragma unroll 1
  for(int sub=0; sub<4; ++sub){
    const int q = w*64 + sub*16 + lq;
    short8v qf = *(const short8v*)(qbh + (size_t)q*CHDX + g*8);
    const float* tbq = tb2 + (size_t)h*NIJ + (size_t)q*NNX;
    float4v s[16];
    // QK^T with bias fused as the MFMA C-operand
    #pragma unroll
    for(int t=0;t<16;++t){
      short8v ak = *(const short8v*)(ktb + (t*16 + lq)*80 + g*16);
      float4v bb = *(const float4v*)(tbq + t*16 + g*4);
      s[t] = MFMA(ak, qf, bb);
    }
    // row max over own 64 + lane groups
    float m = -1e30f;
    #pragma unroll
    for(int t=0;t<16;++t)
      m = fmaxf(m, fmaxf(fmaxf(s[t][0], s[t][1]), fmaxf(s[t][2], s[t][3])));
    m = fmaxf(m, __shfl_xor(m,16));
    m = fmaxf(m, __shfl_xor(m,32));
    float lsum = 0.f;
    #pragma unroll
    for(int t=0;t<16;++t){
      #pragma unroll
      for(int r=0;r<4;++r){ float e = __expf(s[t][r]-m); s[t][r]=e; lsum+=e; }
    }
    lsum += __shfl_xor(lsum,16);
    lsum += __shfl_xor(lsum,32);
    const float linv = 1.0f/lsum;
    // PV directly from registers
    #pragma unroll
    for(int dt=0; dt<2; ++dt){
      float4v acc = (float4v)(0.f);
      #pragma unroll
      for(int c=0;c<8;++c){
        const int vrow = dt*16 + lq;
        short8v av = *(const short8v*)(vtb + vrow*512 + ((16*g + 64*c) ^ ((vrow&7)<<4)));
        uint4 pb;
        pb.x = pk2(s[2*c][0],   s[2*c][1]);
        pb.y = pk2(s[2*c][2],   s[2*c][3]);
        pb.z = pk2(s[2*c+1][0], s[2*c+1][1]);
        pb.w = pk2(s[2*c+1][2], s[2*c+1][3]);
        short8v bp;
        bp[0]=(short)(pb.x&0xffff); bp[1]=(short)(pb.x>>16);
        bp[2]=(short)(pb.y&0xffff); bp[3]=(short)(pb.y>>16);
        bp[4]=(short)(pb.z&0xffff); bp[5]=(short)(pb.z>>16);
        bp[6]=(short)(pb.w&0xffff); bp[7]=(short)(pb.w>>16);
        acc = MFMA(av, bp, acc);
      }
      const size_t eoff = (size_t)q*CHDX + dt*16 + g*4;
      uint2 gw = *(const uint2*)(gbh + eoff);
      float g0 = ubf((unsigned short)(gw.x & 0xffff));
      float g1 = ubf((unsigned short)(gw.x >> 16));
      float g2 = ubf((unsigned short)(gw.y & 0xffff));
      float g3 = ubf((unsigned short)(gw.y >> 16));
      float o0 = acc[0]*linv / (1.f + __expf(-g0));
      float o1 = acc[1]*linv / (1.f + __expf(-g1));
      float o2 = acc[2]*linv / (1.f + __expf(-g2));
      float o3 = acc[3]*linv / (1.f + __expf(-g3));
      uint2 ow; ow.x = pk2(o0,o1); ow.y = pk2(o2,o3);
      *(uint2*)(obh + eoff) = ow;
    }
  }
}

// MFMA o-projection + residual: x += o @ wo + bo. o is head-major [H][NIJ][32].
template<int TRANS>
__global__ __launch_bounds__(256) void k_oprojm(const bf16* __restrict__ ob,
    const bf16* __restrict__ woT, const float* __restrict__ bo, float* __restrict__ x){
  const int tid = threadIdx.x;
  const int w = tid >> 6, l = tid & 63;
  const int lq = l & 15, g = l >> 4;
  const int mbase = blockIdx.x*128 + w*32;
  short8v bx[2][4];
  #pragma unroll
  for(int ms=0; ms<2; ++ms){
    const size_t mrow = mbase + ms*16 + lq;
    #pragma unroll
    for(int kc=0; kc<4; ++kc)
      bx[ms][kc] = *(const short8v*)(ob + ((size_t)kc*NIJ + mrow)*CHDX + g*8);
  }
  #pragma unroll
  for(int nj=0; nj<8; ++nj){
    float4v acc0 = (float4v)(0.f), acc1 = (float4v)(0.f);
    #pragma unroll
    for(int kc=0; kc<4; ++kc){
      short8v aw = *(const short8v*)(woT + (size_t)(nj*16 + lq)*CCX + kc*32 + g*8);
      acc0 = MFMA(aw, bx[0][kc], acc0);
      acc1 = MFMA(aw, bx[1][kc], acc1);
    }
    const int col = nj*16 + 4*g;
    const float4 bo4 = *(const float4*)(bo + col);
    #pragma unroll
    for(int ms=0; ms<2; ++ms){
      const int r = mbase + ms*16 + lq;
      const int ii = r>>8, jj = r&255;
      float* dst = x + (size_t)(TRANS ? (jj*NNX+ii) : r)*CCX + col;
      float4 xv = *(float4*)dst;
      xv.x += ((ms==0)?acc0[0]:acc1[0]) + bo4.x;
      xv.y += ((ms==0)?acc0[1]:acc1[1]) + bo4.y;
      xv.z += ((ms==0)?acc0[2]:acc1[2]) + bo4.z;
      xv.w += ((ms==0)?acc0[3]:acc1[3]) + bo4.w;
      *(float4*)dst = xv;
    }
  }
}

extern "C" void kernel_launch(void* const* d_in, const int* in_sizes, int n_in,
                              void* d_out, int out_size, void* d_ws, size_t ws_size,
                              hipStream_t stream){
  const float* cmap = (const float*)d_in[0];
  char* ws = (char*)d_ws;
  float* x   = (float*)(ws);
  bf16* xln  = (bf16*)(ws + 33554432);
  bf16* ob   = xln;                       // alias: xln dead after k_projm
  bf16* qb   = (bf16*)(ws + 50331648);
  bf16* kb   = (bf16*)(ws + 67108864);
  bf16* vb   = (bf16*)(ws + 83886080);
  bf16* gb   = (bf16*)(ws + 100663296);
  float* tb2 = (float*)(ws + 117440512);
  bf16* wT   = (bf16*)d_out;              // 160KB scratch at head of d_out; k_tout overwrites last
  bf16* woT  = wT + 65536;
  float* outp = (float*)d_out;

  k_tin<<<dim3(8,4,NNX), dim3(32,8), 0, stream>>>(cmap, x);

  for(int p=0;p<2;++p){
    const int b = 1 + 10*p;
    const float* lnw = (const float*)d_in[b+0];
    const float* lnb = (const float*)d_in[b+1];
    const float* wq  = (const float*)d_in[b+2];
    const float* wk  = (const float*)d_in[b+3];
    const float* wv  = (const float*)d_in[b+4];
    const float* wz  = (const float*)d_in[b+5];
    const float* wg  = (const float*)d_in[b+6];
    const float* bg  = (const float*)d_in[b+7];
    const float* wo  = (const float*)d_in[b+8];
    const float* bo  = (const float*)d_in[b+9];

    k_cvtw<<<320, 256, 0, stream>>>(wq, wk, wv, wg, wo, wT);

    if(p==0) k_lntb<0><<<NIJ/4, dim3(64,4), 0, stream>>>(x, lnw, lnb, wz, xln, tb2);
    else     k_lntb<1><<<NIJ/4, dim3(64,4), 0, stream>>>(x, lnw, lnb, wz, xln, tb2);

    k_projm<<<NIJ/128, 256, 0, stream>>>(xln, wT, bg, qb, kb, vb, gb);

    k_attnm<<<dim3(NNX,HHX), 256, 0, stream>>>(qb, kb, vb, gb, tb2, ob);

    if(p==0) k_oprojm<0><<<NIJ/128, 256, 0, stream>>>(ob, woT, bo, x);
    else     k_oprojm<1><<<NIJ/128, 256, 0, stream>>>(ob, woT, bo, x);
  }

  k_tout<<<dim3(8,4,NNX), dim3(32,8), 0, stream>>>(x, outp);
}

// Round 7
// 345.071 us; speedup vs baseline: 1.3401x; 1.2911x over previous
//
#include <hip/hip_runtime.h>
#include <hip/hip_bf16.h>

#define NNX 256
#define CCX 128
#define HHX 4
#define CHDX 32
#define NIJ (NNX*NNX)

typedef __hip_bfloat16 bf16;
typedef __hip_bfloat162 bf162;
typedef __attribute__((ext_vector_type(8))) short short8v;
typedef __attribute__((ext_vector_type(4))) float float4v;
typedef __attribute__((ext_vector_type(4))) unsigned int uint4v;

__device__ __forceinline__ float4v MFMA(short8v a, short8v b, float4v c){
  return __builtin_amdgcn_mfma_f32_16x16x32_bf16(a, b, c, 0, 0, 0);
}

__device__ __forceinline__ unsigned pk2(float a, float b){
  unsigned short ua = __bfloat16_as_ushort(__float2bfloat16(a));
  unsigned short ub = __bfloat16_as_ushort(__float2bfloat16(b));
  return (unsigned)ua | ((unsigned)ub << 16);
}
__device__ __forceinline__ float ubf(unsigned short u){
  return __bfloat162float(__ushort_as_bfloat16(u));
}
__device__ __forceinline__ short8v ntld8(const bf16* p){
  return __builtin_nontemporal_load((const short8v*)p);
}

__device__ __forceinline__ void load8bf16(const bf16* p, float* f){
  const bf162* p2 = (const bf162*)p;
  #pragma unroll
  for(int t=0;t<4;++t){ float2 xy = __bfloat1622float2(p2[t]); f[2*t]=xy.x; f[2*t+1]=xy.y; }
}

// cmap [C, I, J] -> x [I, J, C]
__global__ __launch_bounds__(256) void k_tin(const float* __restrict__ in, float* __restrict__ out){
  __shared__ float t[32][33];
  const int i = blockIdx.z, jt = blockIdx.x, ct = blockIdx.y;
  const int tx = threadIdx.x, ty = threadIdx.y; // 32, 8
  #pragma unroll
  for(int k=0;k<32;k+=8){
    int c = ct*32 + ty + k;
    t[ty+k][tx] = in[(size_t)c*NIJ + (size_t)i*NNX + jt*32 + tx];
  }
  __syncthreads();
  #pragma unroll
  for(int k=0;k<32;k+=8){
    int j = jt*32 + ty + k;
    out[((size_t)i*NNX + j)*CCX + ct*32 + tx] = t[tx][ty+k];
  }
}

// x [I,J,C] -> out [C,I,J]
__global__ __launch_bounds__(256) void k_tout(const float* __restrict__ x, float* __restrict__ out){
  __shared__ float t[32][33];
  const int i = blockIdx.z, jt = blockIdx.x, ct = blockIdx.y;
  const int tx = threadIdx.x, ty = threadIdx.y;
  #pragma unroll
  for(int k=0;k<32;k+=8){
    t[ty+k][tx] = x[((size_t)i*NNX + jt*32+ty+k)*CCX + ct*32 + tx];
  }
  __syncthreads();
  #pragma unroll
  for(int k=0;k<32;k+=8){
    out[(size_t)(ct*32+ty+k)*NIJ + (size_t)i*NNX + jt*32 + tx] = t[tx][ty+k];
  }
}

// fused LayerNorm + triangle-bias projection. One wave per row, thread = 2 channels.
template<int TRANS>
__global__ __launch_bounds__(256) void k_lntb(const float* __restrict__ x,
    const float* __restrict__ w, const float* __restrict__ b,
    const float* __restrict__ wz, bf16* __restrict__ xln, float* __restrict__ tb2){
  const int r = blockIdx.x*4 + threadIdx.y;
  const int ii = r>>8, jj = r&255;
  const float* src = x + (size_t)(TRANS ? (jj*NNX+ii) : r)*CCX;
  const int c = threadIdx.x*2;
  float2 v = *(const float2*)(src+c);
  float s = v.x+v.y, s2 = v.x*v.x+v.y*v.y;
  #pragma unroll
  for(int off=32; off>0; off>>=1){ s += __shfl_xor(s,off); s2 += __shfl_xor(s2,off); }
  float mu = s*0.0078125f;
  float var = s2*0.0078125f - mu*mu;
  float rs = rsqrtf(var+1e-5f);
  float a0 = (v.x-mu)*rs*w[c]+b[c];
  float a1 = (v.y-mu)*rs*w[c+1]+b[c+1];
  bf162 hp; hp.x = __float2bfloat16(a0); hp.y = __float2bfloat16(a1);
  *(bf162*)(xln + (size_t)r*CCX + c) = hp;
  // tb = x_ln @ wz  (wz: [128][4])
  float acc[4];
  #pragma unroll
  for(int hh=0;hh<4;++hh) acc[hh] = a0*wz[c*4+hh] + a1*wz[(c+1)*4+hh];
  #pragma unroll
  for(int off=32; off>0; off>>=1){
    #pragma unroll
    for(int hh=0;hh<4;++hh) acc[hh] += __shfl_xor(acc[hh], off);
  }
  if(threadIdx.x==0){
    #pragma unroll
    for(int hh=0;hh<4;++hh) tb2[(size_t)hh*NIJ + r] = acc[hh];
  }
}

// convert+transpose weights:
//   wT [n][k], n in [0,512): {wq,wk,wv,wg}^T
//   wT+65536: woT [n][k], n in [0,128): wo^T
__global__ __launch_bounds__(256) void k_cvtw(const float* __restrict__ wq,
    const float* __restrict__ wk, const float* __restrict__ wv,
    const float* __restrict__ wg, const float* __restrict__ wo, bf16* __restrict__ wT){
  int idx = blockIdx.x*256 + threadIdx.x;   // 81920
  if(idx < 65536){
    int n = idx >> 7, k = idx & 127;
    const float* W = (n<128)?wq:(n<256)?wk:(n<384)?wv:wg;
    wT[idx] = __float2bfloat16(W[k*CCX + (n&127)]);
  } else {
    int idx2 = idx - 65536;
    int n = idx2 >> 7, k = idx2 & 127;
    wT[idx] = __float2bfloat16(wo[k*CCX + n]);
  }
}

// MFMA projection: out^T tiles = mfma(A = wT tile [16n x 32k], B = xln^T [32k x 16m])
// Outputs q/k/v/g in HEAD-MAJOR layout: [H][NIJ][32].
__global__ __launch_bounds__(256) void k_projm(const bf16* __restrict__ xln,
    const bf16* __restrict__ wT, const float* __restrict__ bg,
    bf16* __restrict__ qb, bf16* __restrict__ kb, bf16* __restrict__ vb, bf16* __restrict__ gb){
  const int tid = threadIdx.x;
  const int w = tid >> 6, l = tid & 63;
  const int lq = l & 15, g = l >> 4;
  const int mbase = blockIdx.x*128 + w*32;
  short8v bx[2][4];
  #pragma unroll
  for(int ms=0; ms<2; ++ms){
    const size_t mrow = mbase + ms*16 + lq;
    #pragma unroll
    for(int kc=0; kc<4; ++kc)
      bx[ms][kc] = *(const short8v*)(xln + mrow*CCX + kc*32 + g*8);
  }
  for(int nj=0; nj<32; ++nj){
    float4v acc0 = (float4v)(0.f), acc1 = (float4v)(0.f);
    #pragma unroll
    for(int kc=0; kc<4; ++kc){
      short8v aw = *(const short8v*)(wT + (size_t)(nj*16 + lq)*CCX + kc*32 + g*8);
      acc0 = MFMA(aw, bx[0][kc], acc0);
      acc1 = MFMA(aw, bx[1][kc], acc1);
    }
    const int mat = nj >> 3;
    const int col = (nj&7)*16 + 4*g;      // [0,128)
    const int hh = col >> 5, cc = col & 31;
    bf16* outp = (mat==0)?qb:(mat==1)?kb:(mat==2)?vb:gb;
    #pragma unroll
    for(int ms=0; ms<2; ++ms){
      const size_t mrow = mbase + ms*16 + lq;
      float v0 = (ms==0)?acc0[0]:acc1[0], v1 = (ms==0)?acc0[1]:acc1[1];
      float v2 = (ms==0)?acc0[2]:acc1[2], v3 = (ms==0)?acc0[3]:acc1[3];
      if(mat==0){ v0*=0.17677669529663687f; v1*=0.17677669529663687f;
                  v2*=0.17677669529663687f; v3*=0.17677669529663687f; }
      if(mat==3){ v0+=bg[col]; v1+=bg[col+1]; v2+=bg[col+2]; v3+=bg[col+3]; }
      uint2 pw; pw.x = pk2(v0,v1); pw.y = pk2(v2,v3);
      *(uint2*)(outp + ((size_t)hh*NIJ + mrow)*CHDX + cc) = pw;
    }
  }
}

// MFMA attention per (i,h). q/k/v/g/o head-major [H][NIJ][32].
// Grid: 1024 1D, XCD-swizzled so each XCD serves one head (tb2 L2-resident).
// Streams (K,V,Q,G,O) are nontemporal; tb2 stays cached.
// O epilogue bounces through the 16B/row holes of the 80B-pitch K LDS to emit
// fully coalesced 16B/lane stores (kills the 8x write amplification).
__global__ __launch_bounds__(256,4) void k_attnm(const bf16* __restrict__ qp,
    const bf16* __restrict__ kp, const bf16* __restrict__ vp,
    const bf16* __restrict__ gp, const float* __restrict__ tb2,
    bf16* __restrict__ op){
  __shared__ unsigned short KsA[256*40];     // 20KB: [0,64)B K data, [64,80)B O-bounce holes
  __shared__ unsigned short VtA[32*256];     // 16KB  V^T [d][kappa], XOR-swizzled
  const int id = blockIdx.x;
  const int xcd = id & 7;
  const int h = xcd >> 1;
  const int i = (id >> 3) | ((xcd & 1) << 7);
  const int tid = threadIdx.x;
  const int w = tid >> 6, l = tid & 63;
  const int lq = l & 15, g = l >> 4;

  const bf16* kbh = kp + ((size_t)h*NIJ + (size_t)i*NNX)*CHDX;
  const bf16* vbh = vp + ((size_t)h*NIJ + (size_t)i*NNX)*CHDX;
  const bf16* qbh = qp + ((size_t)h*NIJ + (size_t)i*NNX)*CHDX;
  const bf16* gbh = gp + ((size_t)h*NIJ + (size_t)i*NNX)*CHDX;
  bf16*       obh = op + ((size_t)h*NIJ + (size_t)i*NNX)*CHDX;

  // ---- stage K (flat coalesced copy, 80B pitch) ----
  #pragma unroll
  for(int it=0; it<4; ++it){
    int idx = tid + it*256;            // [0,1024), 16B each
    int row = idx>>2, seg = (idx&3)*8;
    *(short8v*)(&KsA[row*40 + seg]) = ntld8(kbh + (size_t)idx*8);
  }
  // ---- stage permuted V^T (swizzled scatter from coalesced loads) ----
  {
    char* vtb = (char*)VtA;
    #pragma unroll
    for(int it=0; it<4; ++it){
      int idx = tid + it*256;
      int row = idx>>2, seg = (idx&3)*8;
      short8v vv = ntld8(vbh + (size_t)idx*8);
      const int j = row & 31;
      const int kap = (row & ~31) + 8*((j>>2)&3) + 4*((j>>4)&1) + (j&3);
      #pragma unroll
      for(int e=0;e<8;++e){
        int d = seg+e;
        int off = d*512 + ((2*kap) ^ ((d&7)<<4));
        *(short*)(vtb + off) = vv[e];
      }
    }
  }
  __syncthreads();

  const char* ktb = (const char*)KsA;
  char*       kch = (char*)KsA;
  const char* vtb = (const char*)VtA;

  #pragma unroll 1
  for(int sub=0; sub<4; ++sub){
    const int q0 = w*64 + sub*16;        // wave's 16-row base
    const int q  = q0 + lq;
    short8v qf = ntld8(qbh + (size_t)q*CHDX + g*8);
    const float* tbq = tb2 + (size_t)h*NIJ + (size_t)q*NNX;
    float4v s[16];
    // QK^T with bias fused as the MFMA C-operand
    #pragma unroll
    for(int t=0;t<16;++t){
      short8v ak = *(const short8v*)(ktb + (t*16 + lq)*80 + g*16);
      float4v bb = *(const float4v*)(tbq + t*16 + g*4);
      s[t] = MFMA(ak, qf, bb);
    }
    // row max over own 64 + lane groups
    float m = -1e30f;
    #pragma unroll
    for(int t=0;t<16;++t)
      m = fmaxf(m, fmaxf(fmaxf(s[t][0], s[t][1]), fmaxf(s[t][2], s[t][3])));
    m = fmaxf(m, __shfl_xor(m,16));
    m = fmaxf(m, __shfl_xor(m,32));
    float lsum = 0.f;
    #pragma unroll
    for(int t=0;t<16;++t){
      #pragma unroll
      for(int r=0;r<4;++r){ float e = __expf(s[t][r]-m); s[t][r]=e; lsum+=e; }
    }
    lsum += __shfl_xor(lsum,16);
    lsum += __shfl_xor(lsum,32);
    const float linv = 1.0f/lsum;
    // PV directly from registers; drop (acc*linv) as bf16 into the K-LDS holes
    #pragma unroll
    for(int dt=0; dt<2; ++dt){
      float4v acc = (float4v)(0.f);
      #pragma unroll
      for(int c=0;c<8;++c){
        const int vrow = dt*16 + lq;
        short8v av = *(const short8v*)(vtb + vrow*512 + ((16*g + 64*c) ^ ((vrow&7)<<4)));
        uint4 pb;
        pb.x = pk2(s[2*c][0],   s[2*c][1]);
        pb.y = pk2(s[2*c][2],   s[2*c][3]);
        pb.z = pk2(s[2*c+1][0], s[2*c+1][1]);
        pb.w = pk2(s[2*c+1][2], s[2*c+1][3]);
        short8v bp;
        bp[0]=(short)(pb.x&0xffff); bp[1]=(short)(pb.x>>16);
        bp[2]=(short)(pb.y&0xffff); bp[3]=(short)(pb.y>>16);
        bp[4]=(short)(pb.z&0xffff); bp[5]=(short)(pb.z>>16);
        bp[6]=(short)(pb.w&0xffff); bp[7]=(short)(pb.w>>16);
        acc = MFMA(av, bp, acc);
      }
      uint2 pw; pw.x = pk2(acc[0]*linv, acc[1]*linv);
               pw.y = pk2(acc[2]*linv, acc[3]*linv);
      // hole slot: row (w*64 + lq*4 + 2dt + (g>>1)), byte 64 + (g&1)*8
      *(uint2*)(kch + (size_t)(w*64 + lq*4 + 2*dt + (g>>1))*80 + 64 + (g&1)*8) = pw;
    }
    // coalesced read-back + sigmoid gate + nontemporal store (16B/lane)
    {
      const int r2 = l >> 2, c2 = l & 3;
      short8v ov = *(const short8v*)(kch + (size_t)(w*64 + r2*4 + c2)*80 + 64);
      short8v gv = ntld8(gbh + (size_t)(q0 + r2)*CHDX + c2*8);
      uint4v ow;
      float o0,o1;
      o0 = ubf((unsigned short)ov[0]) / (1.f + __expf(-ubf((unsigned short)gv[0])));
      o1 = ubf((unsigned short)ov[1]) / (1.f + __expf(-ubf((unsigned short)gv[1])));
      ow.x = pk2(o0,o1);
      o0 = ubf((unsigned short)ov[2]) / (1.f + __expf(-ubf((unsigned short)gv[2])));
      o1 = ubf((unsigned short)ov[3]) / (1.f + __expf(-ubf((unsigned short)gv[3])));
      ow.y = pk2(o0,o1);
      o0 = ubf((unsigned short)ov[4]) / (1.f + __expf(-ubf((unsigned short)gv[4])));
      o1 = ubf((unsigned short)ov[5]) / (1.f + __expf(-ubf((unsigned short)gv[5])));
      ow.z = pk2(o0,o1);
      o0 = ubf((unsigned short)ov[6]) / (1.f + __expf(-ubf((unsigned short)gv[6])));
      o1 = ubf((unsigned short)ov[7]) / (1.f + __expf(-ubf((unsigned short)gv[7])));
      ow.w = pk2(o0,o1);
      __builtin_nontemporal_store(ow, (uint4v*)(obh + (size_t)(q0 + r2)*CHDX + c2*8));
    }
  }
}

// MFMA o-projection + residual: x += o @ wo + bo. o is head-major [H][NIJ][32].
template<int TRANS>
__global__ __launch_bounds__(256) void k_oprojm(const bf16* __restrict__ ob,
    const bf16* __restrict__ woT, const float* __restrict__ bo, float* __restrict__ x){
  const int tid = threadIdx.x;
  const int w = tid >> 6, l = tid & 63;
  const int lq = l & 15, g = l >> 4;
  const int mbase = blockIdx.x*128 + w*32;
  short8v bx[2][4];
  #pragma unroll
  for(int ms=0; ms<2; ++ms){
    const size_t mrow = mbase + ms*16 + lq;
    #pragma unroll
    for(int kc=0; kc<4; ++kc)
      bx[ms][kc] = *(const short8v*)(ob + ((size_t)kc*NIJ + mrow)*CHDX + g*8);
  }
  #pragma unroll
  for(int nj=0; nj<8; ++nj){
    float4v acc0 = (float4v)(0.f), acc1 = (float4v)(0.f);
    #pragma unroll
    for(int kc=0; kc<4; ++kc){
      short8v aw = *(const short8v*)(woT + (size_t)(nj*16 + lq)*CCX + kc*32 + g*8);
      acc0 = MFMA(aw, bx[0][kc], acc0);
      acc1 = MFMA(aw, bx[1][kc], acc1);
    }
    const int col = nj*16 + 4*g;
    const float4 bo4 = *(const float4*)(bo + col);
    #pragma unroll
    for(int ms=0; ms<2; ++ms){
      const int r = mbase + ms*16 + lq;
      const int ii = r>>8, jj = r&255;
      float* dst = x + (size_t)(TRANS ? (jj*NNX+ii) : r)*CCX + col;
      float4 xv = *(float4*)dst;
      xv.x += ((ms==0)?acc0[0]:acc1[0]) + bo4.x;
      xv.y += ((ms==0)?acc0[1]:acc1[1]) + bo4.y;
      xv.z += ((ms==0)?acc0[2]:acc1[2]) + bo4.z;
      xv.w += ((ms==0)?acc0[3]:acc1[3]) + bo4.w;
      *(float4*)dst = xv;
    }
  }
}

extern "C" void kernel_launch(void* const* d_in, const int* in_sizes, int n_in,
                              void* d_out, int out_size, void* d_ws, size_t ws_size,
                              hipStream_t stream){
  const float* cmap = (const float*)d_in[0];
  char* ws = (char*)d_ws;
  float* x   = (float*)(ws);
  bf16* xln  = (bf16*)(ws + 33554432);
  bf16* ob   = xln;                       // alias: xln dead after k_projm
  bf16* qb   = (bf16*)(ws + 50331648);
  bf16* kb   = (bf16*)(ws + 67108864);
  bf16* vb   = (bf16*)(ws + 83886080);
  bf16* gb   = (bf16*)(ws + 100663296);
  float* tb2 = (float*)(ws + 117440512);
  bf16* wT   = (bf16*)d_out;              // 160KB scratch at head of d_out; k_tout overwrites last
  bf16* woT  = wT + 65536;
  float* outp = (float*)d_out;

  k_tin<<<dim3(8,4,NNX), dim3(32,8), 0, stream>>>(cmap, x);

  for(int p=0;p<2;++p){
    const int b = 1 + 10*p;
    const float* lnw = (const float*)d_in[b+0];
    const float* lnb = (const float*)d_in[b+1];
    const float* wq  = (const float*)d_in[b+2];
    const float* wk  = (const float*)d_in[b+3];
    const float* wv  = (const float*)d_in[b+4];
    const float* wz  = (const float*)d_in[b+5];
    const float* wg  = (const float*)d_in[b+6];
    const float* bg  = (const float*)d_in[b+7];
    const float* wo  = (const float*)d_in[b+8];
    const float* bo  = (const float*)d_in[b+9];

    k_cvtw<<<320, 256, 0, stream>>>(wq, wk, wv, wg, wo, wT);

    if(p==0) k_lntb<0><<<NIJ/4, dim3(64,4), 0, stream>>>(x, lnw, lnb, wz, xln, tb2);
    else     k_lntb<1><<<NIJ/4, dim3(64,4), 0, stream>>>(x, lnw, lnb, wz, xln, tb2);

    k_projm<<<NIJ/128, 256, 0, stream>>>(xln, wT, bg, qb, kb, vb, gb);

    k_attnm<<<1024, 256, 0, stream>>>(qb, kb, vb, gb, tb2, ob);

    if(p==0) k_oprojm<0><<<NIJ/128, 256, 0, stream>>>(ob, woT, bo, x);
    else     k_oprojm<1><<<NIJ/128, 256, 0, stream>>>(ob, woT, bo, x);
  }

  k_tout<<<dim3(8,4,NNX), dim3(32,8), 0, stream>>>(x, outp);
}

// Round 8
// 240.021 us; speedup vs baseline: 1.9266x; 1.4377x over previous
//
#include <hip/hip_runtime.h>
#include <hip/hip_bf16.h>

#define NNX 256
#define CCX 128
#define HHX 4
#define CHDX 32
#define NIJ (NNX*NNX)

typedef __hip_bfloat16 bf16;
typedef __hip_bfloat162 bf162;
typedef __attribute__((ext_vector_type(8))) short short8v;
typedef __attribute__((ext_vector_type(4))) float float4v;
typedef __attribute__((ext_vector_type(4))) unsigned int uint4v;

__device__ __forceinline__ float4v MFMA(short8v a, short8v b, float4v c){
  return __builtin_amdgcn_mfma_f32_16x16x32_bf16(a, b, c, 0, 0, 0);
}

__device__ __forceinline__ unsigned pk2(float a, float b){
  unsigned short ua = __bfloat16_as_ushort(__float2bfloat16(a));
  unsigned short ub = __bfloat16_as_ushort(__float2bfloat16(b));
  return (unsigned)ua | ((unsigned)ub << 16);
}
__device__ __forceinline__ float ubf(unsigned short u){
  return __bfloat162float(__ushort_as_bfloat16(u));
}

__device__ __forceinline__ void load8bf16(const bf16* p, float* f){
  const bf162* p2 = (const bf162*)p;
  #pragma unroll
  for(int t=0;t<4;++t){ float2 xy = __bfloat1622float2(p2[t]); f[2*t]=xy.x; f[2*t+1]=xy.y; }
}

// cmap [C, I, J] -> x [I, J, C]
__global__ __launch_bounds__(256) void k_tin(const float* __restrict__ in, float* __restrict__ out){
  __shared__ float t[32][33];
  const int i = blockIdx.z, jt = blockIdx.x, ct = blockIdx.y;
  const int tx = threadIdx.x, ty = threadIdx.y; // 32, 8
  #pragma unroll
  for(int k=0;k<32;k+=8){
    int c = ct*32 + ty + k;
    t[ty+k][tx] = in[(size_t)c*NIJ + (size_t)i*NNX + jt*32 + tx];
  }
  __syncthreads();
  #pragma unroll
  for(int k=0;k<32;k+=8){
    int j = jt*32 + ty + k;
    out[((size_t)i*NNX + j)*CCX + ct*32 + tx] = t[tx][ty+k];
  }
}

// x [I,J,C] -> out [C,I,J]
__global__ __launch_bounds__(256) void k_tout(const float* __restrict__ x, float* __restrict__ out){
  __shared__ float t[32][33];
  const int i = blockIdx.z, jt = blockIdx.x, ct = blockIdx.y;
  const int tx = threadIdx.x, ty = threadIdx.y;
  #pragma unroll
  for(int k=0;k<32;k+=8){
    t[ty+k][tx] = x[((size_t)i*NNX + jt*32+ty+k)*CCX + ct*32 + tx];
  }
  __syncthreads();
  #pragma unroll
  for(int k=0;k<32;k+=8){
    out[(size_t)(ct*32+ty+k)*NIJ + (size_t)i*NNX + jt*32 + tx] = t[tx][ty+k];
  }
}

// fused LayerNorm + triangle-bias projection. One wave per row, thread = 2 channels.
template<int TRANS>
__global__ __launch_bounds__(256) void k_lntb(const float* __restrict__ x,
    const float* __restrict__ w, const float* __restrict__ b,
    const float* __restrict__ wz, bf16* __restrict__ xln, float* __restrict__ tb2){
  const int r = blockIdx.x*4 + threadIdx.y;
  const int ii = r>>8, jj = r&255;
  const float* src = x + (size_t)(TRANS ? (jj*NNX+ii) : r)*CCX;
  const int c = threadIdx.x*2;
  float2 v = *(const float2*)(src+c);
  float s = v.x+v.y, s2 = v.x*v.x+v.y*v.y;
  #pragma unroll
  for(int off=32; off>0; off>>=1){ s += __shfl_xor(s,off); s2 += __shfl_xor(s2,off); }
  float mu = s*0.0078125f;
  float var = s2*0.0078125f - mu*mu;
  float rs = rsqrtf(var+1e-5f);
  float a0 = (v.x-mu)*rs*w[c]+b[c];
  float a1 = (v.y-mu)*rs*w[c+1]+b[c+1];
  bf162 hp; hp.x = __float2bfloat16(a0); hp.y = __float2bfloat16(a1);
  *(bf162*)(xln + (size_t)r*CCX + c) = hp;
  // tb = x_ln @ wz  (wz: [128][4])
  float acc[4];
  #pragma unroll
  for(int hh=0;hh<4;++hh) acc[hh] = a0*wz[c*4+hh] + a1*wz[(c+1)*4+hh];
  #pragma unroll
  for(int off=32; off>0; off>>=1){
    #pragma unroll
    for(int hh=0;hh<4;++hh) acc[hh] += __shfl_xor(acc[hh], off);
  }
  if(threadIdx.x==0){
    #pragma unroll
    for(int hh=0;hh<4;++hh) tb2[(size_t)hh*NIJ + r] = acc[hh];
  }
}

// convert+transpose weights:
//   wT [n][k], n in [0,512): {wq,wk,wv,wg}^T
//   wT+65536: woT [n][k], n in [0,128): wo^T
__global__ __launch_bounds__(256) void k_cvtw(const float* __restrict__ wq,
    const float* __restrict__ wk, const float* __restrict__ wv,
    const float* __restrict__ wg, const float* __restrict__ wo, bf16* __restrict__ wT){
  int idx = blockIdx.x*256 + threadIdx.x;   // 81920
  if(idx < 65536){
    int n = idx >> 7, k = idx & 127;
    const float* W = (n<128)?wq:(n<256)?wk:(n<384)?wv:wg;
    wT[idx] = __float2bfloat16(W[k*CCX + (n&127)]);
  } else {
    int idx2 = idx - 65536;
    int n = idx2 >> 7, k = idx2 & 127;
    wT[idx] = __float2bfloat16(wo[k*CCX + n]);
  }
}

// FUSED projection + attention per (i,h). q/k/v/g never touch global memory.
// Phase 1: per wave, load its 64 xln rows as B-frags; mfma against wT head
//          slice (L2-resident) -> Q,K into 80B-pitch LDS, V^T (permuted,
//          swizzled) into LDS, G stays in registers (layout matches PV output).
// Phase 2: attention exactly as before; gate applied in-register pre-bounce;
//          O store coalesced via K-LDS holes.
__global__ __launch_bounds__(256,2) void k_fattn(const bf16* __restrict__ xln,
    const bf16* __restrict__ wT, const float* __restrict__ bg,
    const float* __restrict__ tb2, bf16* __restrict__ op){
  __shared__ unsigned short Qs[256*40];      // 20KB  Q row-major [q][d], 80B pitch
  __shared__ unsigned short Ks[256*40];      // 20KB  K row-major [k][d] + O-bounce holes
  __shared__ unsigned short Vt[32*256];      // 16KB  V^T [d][kappa], XOR-swizzled
  const int id = blockIdx.x;
  const int i = id >> 2, h = id & 3;
  const int tid = threadIdx.x;
  const int w = tid >> 6, l = tid & 63;
  const int lq = l & 15, g = l >> 4;
  const int mb = w*64;

  // ---- phase 1: projection ----
  short8v bx[4][4];
  #pragma unroll
  for(int ms=0; ms<4; ++ms){
    const size_t row = (size_t)i*NNX + mb + ms*16 + lq;
    #pragma unroll
    for(int kc=0; kc<4; ++kc)
      bx[ms][kc] = *(const short8v*)(xln + row*CCX + kc*32 + g*8);
  }
  float4v greg[2][4];
  char* qsb = (char*)Qs;
  char* ksb = (char*)Ks;
  char* vtb = (char*)Vt;
  #pragma unroll
  for(int mat=0; mat<4; ++mat){
    #pragma unroll
    for(int half=0; half<2; ++half){
      const int n0 = mat*128 + h*32 + half*16;
      float4v acc[4];
      #pragma unroll
      for(int ms=0; ms<4; ++ms) acc[ms] = (float4v)(0.f);
      #pragma unroll
      for(int kc=0; kc<4; ++kc){
        short8v aw = *(const short8v*)(wT + (size_t)(n0 + lq)*CCX + kc*32 + g*8);
        #pragma unroll
        for(int ms=0; ms<4; ++ms) acc[ms] = MFMA(aw, bx[ms][kc], acc[ms]);
      }
      if(mat==0){        // Q: scale, to LDS
        #pragma unroll
        for(int ms=0; ms<4; ++ms){
          const int row = mb + ms*16 + lq;
          uint2 pw; pw.x = pk2(acc[ms][0]*0.17677669529663687f, acc[ms][1]*0.17677669529663687f);
                    pw.y = pk2(acc[ms][2]*0.17677669529663687f, acc[ms][3]*0.17677669529663687f);
          *(uint2*)(qsb + (size_t)row*80 + half*32 + g*8) = pw;
        }
      } else if(mat==1){ // K: to LDS
        #pragma unroll
        for(int ms=0; ms<4; ++ms){
          const int row = mb + ms*16 + lq;
          uint2 pw; pw.x = pk2(acc[ms][0], acc[ms][1]);
                    pw.y = pk2(acc[ms][2], acc[ms][3]);
          *(uint2*)(ksb + (size_t)row*80 + half*32 + g*8) = pw;
        }
      } else if(mat==2){ // V: permuted+swizzled V^T scatter
        #pragma unroll
        for(int ms=0; ms<4; ++ms){
          const int k = mb + ms*16 + lq;
          const int j = k & 31;
          const int kap = (k & ~31) + 8*((j>>2)&3) + 4*((j>>4)&1) + (j&3);
          #pragma unroll
          for(int r=0; r<4; ++r){
            const int d = half*16 + 4*g + r;
            const int off = d*512 + ((2*kap) ^ ((d&7)<<4));
            *(unsigned short*)(vtb + off) = __bfloat16_as_ushort(__float2bfloat16(acc[ms][r]));
          }
        }
      } else {           // G: + bias, keep in registers (layout matches PV out)
        const float4 bg4 = *(const float4*)(bg + h*32 + half*16 + 4*g);
        #pragma unroll
        for(int ms=0; ms<4; ++ms){
          float4v t = acc[ms];
          t[0]+=bg4.x; t[1]+=bg4.y; t[2]+=bg4.z; t[3]+=bg4.w;
          greg[half][ms] = t;
        }
      }
    }
  }
  __syncthreads();

  // ---- phase 2: attention ----
  bf16* obh = op + ((size_t)h*NIJ + (size_t)i*NNX)*CHDX;
  #pragma unroll 1
  for(int sub=0; sub<4; ++sub){
    const int q0 = mb + sub*16;
    const int q  = q0 + lq;
    short8v qf = *(const short8v*)(qsb + (size_t)q*80 + g*16);
    const float* tbq = tb2 + (size_t)h*NIJ + (size_t)q*NNX;
    float4v s[16];
    #pragma unroll
    for(int t=0;t<16;++t){
      short8v ak = *(const short8v*)(ksb + (size_t)(t*16 + lq)*80 + g*16);
      float4v bb = *(const float4v*)(tbq + t*16 + g*4);
      s[t] = MFMA(ak, qf, bb);
    }
    float m = -1e30f;
    #pragma unroll
    for(int t=0;t<16;++t)
      m = fmaxf(m, fmaxf(fmaxf(s[t][0], s[t][1]), fmaxf(s[t][2], s[t][3])));
    m = fmaxf(m, __shfl_xor(m,16));
    m = fmaxf(m, __shfl_xor(m,32));
    float lsum = 0.f;
    #pragma unroll
    for(int t=0;t<16;++t){
      #pragma unroll
      for(int r=0;r<4;++r){ float e = __expf(s[t][r]-m); s[t][r]=e; lsum+=e; }
    }
    lsum += __shfl_xor(lsum,16);
    lsum += __shfl_xor(lsum,32);
    const float linv = 1.0f/lsum;
    #pragma unroll
    for(int dt=0; dt<2; ++dt){
      float4v acc = (float4v)(0.f);
      #pragma unroll
      for(int c=0;c<8;++c){
        const int vrow = dt*16 + lq;
        short8v av = *(const short8v*)(vtb + (size_t)vrow*512 + ((16*g + 64*c) ^ ((vrow&7)<<4)));
        uint4 pb;
        pb.x = pk2(s[2*c][0],   s[2*c][1]);
        pb.y = pk2(s[2*c][2],   s[2*c][3]);
        pb.z = pk2(s[2*c+1][0], s[2*c+1][1]);
        pb.w = pk2(s[2*c+1][2], s[2*c+1][3]);
        short8v bp;
        bp[0]=(short)(pb.x&0xffff); bp[1]=(short)(pb.x>>16);
        bp[2]=(short)(pb.y&0xffff); bp[3]=(short)(pb.y>>16);
        bp[4]=(short)(pb.z&0xffff); bp[5]=(short)(pb.z>>16);
        bp[6]=(short)(pb.w&0xffff); bp[7]=(short)(pb.w>>16);
        acc = MFMA(av, bp, acc);
      }
      // gate in-register (greg layout matches: lane lq = q-row, reg r = d)
      const float4v gg = greg[dt][sub];
      float o0 = acc[0]*linv / (1.f + __expf(-gg[0]));
      float o1 = acc[1]*linv / (1.f + __expf(-gg[1]));
      float o2 = acc[2]*linv / (1.f + __expf(-gg[2]));
      float o3 = acc[3]*linv / (1.f + __expf(-gg[3]));
      uint2 pw; pw.x = pk2(o0,o1); pw.y = pk2(o2,o3);
      *(uint2*)(ksb + (size_t)(mb + lq*4 + 2*dt + (g>>1))*80 + 64 + (g&1)*8) = pw;
    }
    // coalesced read-back + nontemporal store (16B/lane)
    {
      const int r2 = l >> 2, c2 = l & 3;
      uint4v ow = *(const uint4v*)(ksb + (size_t)(mb + r2*4 + c2)*80 + 64);
      __builtin_nontemporal_store(ow, (uint4v*)(obh + (size_t)(q0 + r2)*CHDX + c2*8));
    }
  }
}

// MFMA o-projection + residual: x += o @ wo + bo. o is head-major [H][NIJ][32].
template<int TRANS>
__global__ __launch_bounds__(256) void k_oprojm(const bf16* __restrict__ ob,
    const bf16* __restrict__ woT, const float* __restrict__ bo, float* __restrict__ x){
  const int tid = threadIdx.x;
  const int w = tid >> 6, l = tid & 63;
  const int lq = l & 15, g = l >> 4;
  const int mbase = blockIdx.x*128 + w*32;
  short8v bx[2][4];
  #pragma unroll
  for(int ms=0; ms<2; ++ms){
    const size_t mrow = mbase + ms*16 + lq;
    #pragma unroll
    for(int kc=0; kc<4; ++kc)
      bx[ms][kc] = *(const short8v*)(ob + ((size_t)kc*NIJ + mrow)*CHDX + g*8);
  }
  #pragma unroll
  for(int nj=0; nj<8; ++nj){
    float4v acc0 = (float4v)(0.f), acc1 = (float4v)(0.f);
    #pragma unroll
    for(int kc=0; kc<4; ++kc){
      short8v aw = *(const short8v*)(woT + (size_t)(nj*16 + lq)*CCX + kc*32 + g*8);
      acc0 = MFMA(aw, bx[0][kc], acc0);
      acc1 = MFMA(aw, bx[1][kc], acc1);
    }
    const int col = nj*16 + 4*g;
    const float4 bo4 = *(const float4*)(bo + col);
    #pragma unroll
    for(int ms=0; ms<2; ++ms){
      const int r = mbase + ms*16 + lq;
      const int ii = r>>8, jj = r&255;
      float* dst = x + (size_t)(TRANS ? (jj*NNX+ii) : r)*CCX + col;
      float4 xv = *(float4*)dst;
      xv.x += ((ms==0)?acc0[0]:acc1[0]) + bo4.x;
      xv.y += ((ms==0)?acc0[1]:acc1[1]) + bo4.y;
      xv.z += ((ms==0)?acc0[2]:acc1[2]) + bo4.z;
      xv.w += ((ms==0)?acc0[3]:acc1[3]) + bo4.w;
      *(float4*)dst = xv;
    }
  }
}

extern "C" void kernel_launch(void* const* d_in, const int* in_sizes, int n_in,
                              void* d_out, int out_size, void* d_ws, size_t ws_size,
                              hipStream_t stream){
  const float* cmap = (const float*)d_in[0];
  char* ws = (char*)d_ws;
  float* x   = (float*)(ws);
  bf16* xln  = (bf16*)(ws + 33554432);
  bf16* ob   = (bf16*)(ws + 50331648);
  float* tb2 = (float*)(ws + 117440512);
  bf16* wT   = (bf16*)d_out;              // 160KB scratch at head of d_out; k_tout overwrites last
  bf16* woT  = wT + 65536;
  float* outp = (float*)d_out;

  k_tin<<<dim3(8,4,NNX), dim3(32,8), 0, stream>>>(cmap, x);

  for(int p=0;p<2;++p){
    const int b = 1 + 10*p;
    const float* lnw = (const float*)d_in[b+0];
    const float* lnb = (const float*)d_in[b+1];
    const float* wq  = (const float*)d_in[b+2];
    const float* wk  = (const float*)d_in[b+3];
    const float* wv  = (const float*)d_in[b+4];
    const float* wz  = (const float*)d_in[b+5];
    const float* wg  = (const float*)d_in[b+6];
    const float* bg  = (const float*)d_in[b+7];
    const float* wo  = (const float*)d_in[b+8];
    const float* bo  = (const float*)d_in[b+9];

    k_cvtw<<<320, 256, 0, stream>>>(wq, wk, wv, wg, wo, wT);

    if(p==0) k_lntb<0><<<NIJ/4, dim3(64,4), 0, stream>>>(x, lnw, lnb, wz, xln, tb2);
    else     k_lntb<1><<<NIJ/4, dim3(64,4), 0, stream>>>(x, lnw, lnb, wz, xln, tb2);

    k_fattn<<<1024, 256, 0, stream>>>(xln, wT, bg, tb2, ob);

    if(p==0) k_oprojm<0><<<NIJ/128, 256, 0, stream>>>(ob, woT, bo, x);
    else     k_oprojm<1><<<NIJ/128, 256, 0, stream>>>(ob, woT, bo, x);
  }

  k_tout<<<dim3(8,4,NNX), dim3(32,8), 0, stream>>>(x, outp);
}